// Round 10
// baseline (162.305 us; speedup 1.0000x reference)
//
#include <hip/hip_runtime.h>
#include <hip/hip_bf16.h>

#define B_   2
#define N_   2048
#define DM_  1024
#define H_   16
#define DK_  64
#define BLK_ 128
#define TB_  16

typedef unsigned short u16;
typedef unsigned int   u32;
using bf16x8 = __attribute__((ext_vector_type(8))) __bf16;
using f32x4  = __attribute__((ext_vector_type(4))) float;

#define PPAD 136   // Ps rows of 128 bf16 (+8)
#define OPAD 68    // Os rows of 64 fp32 (+4), epilogue overlay only

__device__ __forceinline__ u32 pack_bf16(float a, float b) {
  __hip_bfloat162 h = __float22bfloat162_rn(make_float2(a, b));
  u32 u; __builtin_memcpy(&u, &h, 4); return u;
}
__device__ __forceinline__ bf16x8 pack8(float4 f0, float4 f1, float sc) {
  u32 w[4];
  w[0] = pack_bf16(f0.x * sc, f0.y * sc); w[1] = pack_bf16(f0.z * sc, f0.w * sc);
  w[2] = pack_bf16(f1.x * sc, f1.y * sc); w[3] = pack_bf16(f1.z * sc, f1.w * sc);
  bf16x8 r; __builtin_memcpy(&r, w, 16); return r;
}

// ---------------- fused pre-pass: KV images (blocks 0..511) + flags (512..1023) ----------------
// kimg: 128 rows x 64 bf16 (128B/row), 16B-chunk index XOR'd with (row&7).
// vimg: 64 d-rows x 128 bf16 (256B/row), chunk index XOR'd with (d&7).
// attn copies these verbatim to LDS -> swizzle lands in LDS for conflict-light
// b128 fragment reads (R9-measured: 4.45M -> 2.5M). Fusion saves a serial kernel
// boundary (R9-measured: ~12us total).
__global__ void prepass_kernel(const float* __restrict__ k, const float* __restrict__ v,
                               const int* __restrict__ mask, const int* __restrict__ bs,
                               u16* __restrict__ kimg, u16* __restrict__ vimg,
                               int* __restrict__ flags) {
  __shared__ u16 tile[BLK_][DK_ + 2];
  __shared__ int sAll[4], sAny[4];
  const int blk0 = blockIdx.x;
  const int t = threadIdx.x;
  if (blk0 < 512) {
    // ---- KV image build ----
    const int nb = blk0 & 15, h = (blk0 >> 4) & 15, b = blk0 >> 8;
    const size_t obase = ((size_t)((b * H_ + h) * TB_ + nb)) * 8192;
    const int rr = t >> 4, cc = (t & 15) * 4;
    {
      const float* kg = k + ((size_t)(b * N_ + nb * BLK_)) * DM_ + h * DK_;
      u16* kd = kimg + obase;
#pragma unroll
      for (int i = 0; i < 8; ++i) {
        const int r = rr + i * 16;
        const float4 f = *(const float4*)(kg + (size_t)r * DM_ + cc);
        const int so = ((((cc >> 3) ^ (r & 7)) << 3) | (cc & 4));
        *(uint2*)(kd + r * 64 + so) = make_uint2(pack_bf16(f.x, f.y), pack_bf16(f.z, f.w));
      }
    }
    {
      const float* vg = v + ((size_t)(b * N_ + nb * BLK_)) * DM_ + h * DK_;
#pragma unroll
      for (int i = 0; i < 8; ++i) {
        const int r = rr + i * 16;
        const float4 f = *(const float4*)(vg + (size_t)r * DM_ + cc);
        *(u32*)(&tile[r][cc])     = pack_bf16(f.x, f.y);
        *(u32*)(&tile[r][cc + 2]) = pack_bf16(f.z, f.w);
      }
      __syncthreads();
      // d = t&63: 64 distinct d per wave -> conflict-light column gather (R4 fix)
      const int d = t & 63, n0 = (t >> 6) * 32;
      u16* og = vimg + obase + d * 128;
#pragma unroll
      for (int j = 0; j < 32; j += 8) {
        u16 tmp[8];
#pragma unroll
        for (int x = 0; x < 8; ++x) tmp[x] = tile[n0 + j + x][d];
        uint4 w; __builtin_memcpy(&w, tmp, 16);
        const int chunk = (n0 + j) >> 3;
        *(uint4*)(og + ((chunk ^ (d & 7)) << 3)) = w;
      }
    }
  } else {
    // ---- mask + block_sparse -> flags {0,1,2} ----
    const int blk = blk0 - 512;
    const int kb = blk % TB_, qb = (blk / TB_) % TB_, b = blk / (TB_ * TB_);
    const int* mg = mask + (size_t)b * N_ * N_ + (size_t)(qb * BLK_) * N_ + kb * BLK_;
    int all1 = 1, any1 = 0;
    for (int i = t; i < BLK_ * BLK_ / 4; i += 256) {
      const int r = i >> 5, c = (i & 31) * 4;
      const int4 mv = *(const int4*)(mg + (size_t)r * N_ + c);
      all1 &= (mv.x != 0) & (mv.y != 0) & (mv.z != 0) & (mv.w != 0);
      any1 |= (mv.x != 0) | (mv.y != 0) | (mv.z != 0) | (mv.w != 0);
    }
    const int wv = t >> 6;
    const int wAll = __all(all1), wAny = __any(any1);
    if ((t & 63) == 0) { sAll[wv] = wAll; sAny[wv] = wAny; }
    __syncthreads();
    if (t == 0) {
      const int A = sAll[0] & sAll[1] & sAll[2] & sAll[3];
      const int O = sAny[0] | sAny[1] | sAny[2] | sAny[3];
      int f = 0;
      if (bs[qb * TB_ + kb] != 0 && O) f = A ? 1 : 2;
      flags[blk] = f;
    }
  }
}

// ---------------- main: block-sparse flash attention ----------------
// Final consolidation -- every component is the measured winner of an A/B this
// session: REGISTER staging (R4: 51.3us vs async global_load_lds R7/R9: 57us --
// the DMA drain at the barrier stalls all waves with zero intervening work,
// while register staging's progressive vmcnt ds_writes overlap load latency);
// pre-swizzled contiguous 16KB image source (R9: simpler addressing than R4's
// strided V, conflict-light reads 4.45M->2.5M); Ps wave-private LDS round-trip
// (R4/R7: beats shuffle-P by 6us); 128q WG grid 512 (beats split-Q R5/R8);
// fused pre-pass (R9: -12us total); setprio + defer-rescale (R4: ~3us).
// LDS = 16K(K) + 16K(V) + 34.8K(Ps) = 67584 B -> 2 WG/CU.
__global__ __launch_bounds__(256, 2)
void attn_kernel(const float* __restrict__ q_, const u16* __restrict__ kimg,
                 const u16* __restrict__ vimg, const float* __restrict__ tau_p,
                 const int* __restrict__ mask, const int* __restrict__ flags,
                 float* __restrict__ o_out, float* __restrict__ l_out,
                 float* __restrict__ m_out) {
  __shared__ __align__(16) u16 lds[8192 + 8192 + BLK_ * PPAD];   // 67584 B
  u16* Ps  = lds + 16384;                 // 128 x PPAD (wave-private 32-row stripes)
  float* Os = (float*)lds;                // 128 x OPAD fp32 epilogue overlay (34816 B)

  const int idx = blockIdx.x;
  const int bh = idx & 31, qb128 = idx >> 5;
  const int b = bh >> 4, h = bh & 15;
  const int t = threadIdx.x;
  const int wave = t >> 6, lane = t & 63, quad = lane >> 4, col = lane & 15;

  // active-kb bitmasks (uniform across the WG)
  const int* flg = flags + (b * TB_ + qb128) * TB_;
  u32 actmask = 0, mixmask = 0;
#pragma unroll
  for (int i = 0; i < TB_; ++i) {
    const int f = flg[i];
    actmask |= (f != 0) ? (1u << i) : 0u;
    mixmask |= (f == 2) ? (1u << i) : 0u;
  }

  const u16* kpl = kimg + (size_t)(b * H_ + h) * TB_ * 8192;
  const u16* vpl = vimg + (size_t)(b * H_ + h) * TB_ * 8192;

  int qg[2];
  qg[0] = qb128 * BLK_ + wave * 32 + col;
  qg[1] = qg[0] + 16;

  // Q B-fragments from fp32 global (one-time; scale + log2e folded)
  const float qscale = tau_p[0] * 0.125f * 1.44269504f;
  bf16x8 bq[2][2];
#pragma unroll
  for (int nt = 0; nt < 2; ++nt) {
    const float* qr = q_ + ((size_t)(b * N_ + qg[nt])) * DM_ + h * DK_;
#pragma unroll
    for (int half = 0; half < 2; ++half) {
      const float4 f0 = *(const float4*)(qr + half * 32 + quad * 8);
      const float4 f1 = *(const float4*)(qr + half * 32 + quad * 8 + 4);
      bq[nt][half] = pack8(f0, f1, qscale);
    }
  }

  float m_run[2]  = {-INFINITY, -INFINITY};   // softmax base (lags true max <= THR)
  float m_true[2] = {-INFINITY, -INFINITY};   // true running max (for l/m outputs)
  float l_run[2] = {0.f, 0.f};
  f32x4 oacc[2][4];
#pragma unroll
  for (int nt = 0; nt < 2; ++nt)
#pragma unroll
    for (int mt = 0; mt < 4; ++mt) oacc[nt][mt] = (f32x4){0.f, 0.f, 0.f, 0.f};

  const int s8 = col & 7;                 // (fragment row) & 7 for K and V reads
  const int a0o = (quad ^ s8) << 3;       // swizzled 16B-chunk offset (u16 units)

  u32 rem = actmask;
  while (rem) {
    const int cur = (int)__builtin_ctz(rem);
    rem &= rem - 1;
    const int mix = (mixmask >> cur) & 1;

    __syncthreads();  // previous iter's K/V fragment reads complete
    // ---- register staging from contiguous image blocks (R4-style, L2-resident;
    //      compiler interleaves ds_writes under progressive vmcnt) ----
    {
      const u16* ks = kpl + (size_t)cur * 8192;
      const u16* vs = vpl + (size_t)cur * 8192;
      uint4 kr[4], vr[4];
#pragma unroll
      for (int j = 0; j < 4; ++j) {
        const int i = (t + 256 * j) * 8;
        kr[j] = *(const uint4*)(ks + i);
        vr[j] = *(const uint4*)(vs + i);
      }
#pragma unroll
      for (int j = 0; j < 4; ++j) {
        const int i = (t + 256 * j) * 8;
        *(uint4*)(lds + i) = kr[j];
        *(uint4*)(lds + 8192 + i) = vr[j];
      }
    }
    __syncthreads();

    // ---- per q-tile: S^T = K.Q^T (swizzled K reads), softmax, P -> LDS ----
#pragma unroll
    for (int nt = 0; nt < 2; ++nt) {
      f32x4 st[8];
      __builtin_amdgcn_s_setprio(1);
#pragma unroll
      for (int kt = 0; kt < 8; ++kt) {
        const u16* krow = lds + (kt * 16 + col) * 64;
        const bf16x8 a0 = *(const bf16x8*)(krow + a0o);
        const bf16x8 a1 = *(const bf16x8*)(krow + (a0o ^ 32));
        f32x4 c = (f32x4){0.f, 0.f, 0.f, 0.f};
        c = __builtin_amdgcn_mfma_f32_16x16x32_bf16(a0, bq[nt][0], c, 0, 0, 0);
        c = __builtin_amdgcn_mfma_f32_16x16x32_bf16(a1, bq[nt][1], c, 0, 0, 0);
        st[kt] = c;
      }
      __builtin_amdgcn_s_setprio(0);
      if (mix) {  // token mask (not taken with all-ones mask)
        const int* mg = mask + (size_t)b * N_ * N_ + (size_t)qg[nt] * N_ + cur * BLK_;
#pragma unroll
        for (int kt = 0; kt < 8; ++kt) {
          const int4 mv = *(const int4*)(mg + kt * 16 + quad * 4);
          if (!mv.x) st[kt][0] = -1e30f;
          if (!mv.y) st[kt][1] = -1e30f;
          if (!mv.z) st[kt][2] = -1e30f;
          if (!mv.w) st[kt][3] = -1e30f;
        }
      }
      float mx = -INFINITY;
#pragma unroll
      for (int kt = 0; kt < 8; ++kt)
        mx = fmaxf(mx, fmaxf(fmaxf(st[kt][0], st[kt][1]), fmaxf(st[kt][2], st[kt][3])));
      mx = fmaxf(mx, __shfl_xor(mx, 16, 64));
      mx = fmaxf(mx, __shfl_xor(mx, 32, 64));
      m_true[nt] = fmaxf(m_true[nt], mx);

      // T13 defer-rescale: skip the O/l rescale unless a row grew past THR=8 (log2).
      const float mold = m_run[nt];
      float mnew = mold;
      if (!__all(mx <= mold + 8.f)) {
        mnew = fmaxf(mold, mx);
        const float alpha = __builtin_amdgcn_exp2f(mold - mnew);
        l_run[nt] *= alpha;
#pragma unroll
        for (int mt = 0; mt < 4; ++mt)
#pragma unroll
          for (int r = 0; r < 4; ++r) oacc[nt][mt][r] *= alpha;
        m_run[nt] = mnew;
      }

      const int qloc = wave * 32 + nt * 16 + col;
      float s = 0.f;
      if (!mix) {
#pragma unroll
        for (int kt = 0; kt < 8; ++kt) {
          const float p0 = __builtin_amdgcn_exp2f(st[kt][0] - mnew);
          const float p1 = __builtin_amdgcn_exp2f(st[kt][1] - mnew);
          const float p2 = __builtin_amdgcn_exp2f(st[kt][2] - mnew);
          const float p3 = __builtin_amdgcn_exp2f(st[kt][3] - mnew);
          s += (p0 + p1) + (p2 + p3);
          *(uint2*)(Ps + qloc * PPAD + kt * 16 + quad * 4) =
              make_uint2(pack_bf16(p0, p1), pack_bf16(p2, p3));
        }
      } else {
#pragma unroll
        for (int kt = 0; kt < 8; ++kt) {
          const float p0 = st[kt][0] <= -1e29f ? 0.f : __builtin_amdgcn_exp2f(st[kt][0] - mnew);
          const float p1 = st[kt][1] <= -1e29f ? 0.f : __builtin_amdgcn_exp2f(st[kt][1] - mnew);
          const float p2 = st[kt][2] <= -1e29f ? 0.f : __builtin_amdgcn_exp2f(st[kt][2] - mnew);
          const float p3 = st[kt][3] <= -1e29f ? 0.f : __builtin_amdgcn_exp2f(st[kt][3] - mnew);
          s += (p0 + p1) + (p2 + p3);
          *(uint2*)(Ps + qloc * PPAD + kt * 16 + quad * 4) =
              make_uint2(pack_bf16(p0, p1), pack_bf16(p2, p3));
        }
      }
      s += __shfl_xor(s, 16, 64);
      s += __shfl_xor(s, 32, 64);
      l_run[nt] += s;
    }

    // ---- O^T += V^T . P^T ; P from wave-private LDS, swizzled V reads ----
    __builtin_amdgcn_s_setprio(1);
#pragma unroll
    for (int ks = 0; ks < 4; ++ks) {
      bf16x8 bfrag[2];
#pragma unroll
      for (int nt = 0; nt < 2; ++nt)
        bfrag[nt] = *(const bf16x8*)(Ps + (wave * 32 + nt * 16 + col) * PPAD + ks * 32 + quad * 8);
#pragma unroll
      for (int mt = 0; mt < 4; ++mt) {
        const bf16x8 av =
            *(const bf16x8*)(lds + 8192 + (mt * 16 + col) * 128 + (((ks * 4 + quad) ^ s8) << 3));
        oacc[0][mt] = __builtin_amdgcn_mfma_f32_16x16x32_bf16(av, bfrag[0], oacc[0][mt], 0, 0, 0);
        oacc[1][mt] = __builtin_amdgcn_mfma_f32_16x16x32_bf16(av, bfrag[1], oacc[1][mt], 0, 0, 0);
      }
    }
    __builtin_amdgcn_s_setprio(0);
  }

  // ---- epilogue: normalize, transpose O through LDS overlay, coalesced writes ----
  __syncthreads();  // all waves done with K/V/Ps before Os overlay
#pragma unroll
  for (int nt = 0; nt < 2; ++nt) {
    const float inv = l_run[nt] > 0.f ? 1.f / l_run[nt] : 1.f;
    const int qloc = wave * 32 + nt * 16 + col;
#pragma unroll
    for (int mt = 0; mt < 4; ++mt) {
      float4 w = make_float4(oacc[nt][mt][0] * inv, oacc[nt][mt][1] * inv,
                             oacc[nt][mt][2] * inv, oacc[nt][mt][3] * inv);
      *(float4*)(Os + qloc * OPAD + mt * 16 + quad * 4) = w;
    }
  }
  __syncthreads();
  float* ob = o_out + ((size_t)(b * N_ + qb128 * BLK_)) * DM_ + h * DK_;
#pragma unroll
  for (int j = 0; j < 8; ++j) {
    const int i = t + 256 * j;
    const int r = i >> 4, c4 = (i & 15) * 4;
    const float4 w = *(const float4*)(Os + r * OPAD + c4);
    *(float4*)(ob + (size_t)r * DM_ + c4) = w;
  }
  if (quad == 0) {
#pragma unroll
    for (int nt = 0; nt < 2; ++nt) {
      const size_t oi = (size_t)(b * H_ + h) * N_ + qg[nt];
      const float lv = l_run[nt] > 0.f
          ? l_run[nt] * __builtin_amdgcn_exp2f(m_run[nt] - m_true[nt]) : 0.f;
      l_out[oi] = lv;
      m_out[oi] = l_run[nt] > 0.f ? m_true[nt] * 0.69314718056f : -INFINITY;
    }
  }
}

extern "C" void kernel_launch(void* const* d_in, const int* in_sizes, int n_in,
                              void* d_out, int out_size, void* d_ws, size_t ws_size,
                              hipStream_t stream) {
  const float* q   = (const float*)d_in[0];
  const float* k   = (const float*)d_in[1];
  const float* v   = (const float*)d_in[2];
  const float* tau = (const float*)d_in[3];
  const int* mask  = (const int*)d_in[4];
  const int* bs    = (const int*)d_in[5];
  float* out = (float*)d_out;

  const size_t plane = (size_t)B_ * H_ * N_ * DK_;  // == B*H*TB*8192
  u16* kimg = (u16*)d_ws;
  u16* vimg = kimg + plane;
  int* flags = (int*)(vimg + plane);

  prepass_kernel<<<dim3(1024), 256, 0, stream>>>(k, v, mask, bs, kimg, vimg, flags);

  float* o_out = out;
  float* l_out = out + (size_t)B_ * N_ * DM_;
  float* m_out = l_out + (size_t)B_ * H_ * N_;
  attn_kernel<<<dim3(TB_ * 32), 256, 0, stream>>>(q, kimg, vimg, tau, mask, flags,
                                                  o_out, l_out, m_out);
}

// Round 11
// 159.471 us; speedup vs baseline: 1.0178x; 1.0178x over previous
//
#include <hip/hip_runtime.h>
#include <hip/hip_bf16.h>

#define B_   2
#define N_   2048
#define DM_  1024
#define H_   16
#define DK_  64
#define BLK_ 128
#define TB_  16

typedef unsigned short u16;
typedef unsigned int   u32;
using bf16x8 = __attribute__((ext_vector_type(8))) __bf16;
using f32x4  = __attribute__((ext_vector_type(4))) float;

#define PPAD 136   // Ps rows of 128 bf16 (+8)
#define OPAD 68    // Os rows of 64 fp32 (+4), epilogue overlay only

__device__ __forceinline__ u32 pack_bf16(float a, float b) {
  __hip_bfloat162 h = __float22bfloat162_rn(make_float2(a, b));
  u32 u; __builtin_memcpy(&u, &h, 4); return u;
}
__device__ __forceinline__ bf16x8 pack8(float4 f0, float4 f1, float sc) {
  u32 w[4];
  w[0] = pack_bf16(f0.x * sc, f0.y * sc); w[1] = pack_bf16(f0.z * sc, f0.w * sc);
  w[2] = pack_bf16(f1.x * sc, f1.y * sc); w[3] = pack_bf16(f1.z * sc, f1.w * sc);
  bf16x8 r; __builtin_memcpy(&r, w, 16); return r;
}

// ---------------- fused pre-pass: KV images (blocks 0..511) + flags (512..1023) ----------------
// kimg: 128 rows x 64 bf16 (128B/row), 16B-chunk index XOR'd with (row&7).
// vimg: 64 d-rows x 128 bf16 (256B/row), chunk index XOR'd with (d&7).
// attn copies these verbatim to LDS -> swizzle lands in LDS for conflict-light
// b128 fragment reads (R9/R10-measured). Fusion saves a serial kernel boundary.
__global__ void prepass_kernel(const float* __restrict__ k, const float* __restrict__ v,
                               const int* __restrict__ mask, const int* __restrict__ bs,
                               u16* __restrict__ kimg, u16* __restrict__ vimg,
                               int* __restrict__ flags) {
  __shared__ u16 tile[BLK_][DK_ + 2];
  __shared__ int sAll[4], sAny[4];
  const int blk0 = blockIdx.x;
  const int t = threadIdx.x;
  if (blk0 < 512) {
    // ---- KV image build ----
    const int nb = blk0 & 15, h = (blk0 >> 4) & 15, b = blk0 >> 8;
    const size_t obase = ((size_t)((b * H_ + h) * TB_ + nb)) * 8192;
    const int rr = t >> 4, cc = (t & 15) * 4;
    {
      const float* kg = k + ((size_t)(b * N_ + nb * BLK_)) * DM_ + h * DK_;
      u16* kd = kimg + obase;
#pragma unroll
      for (int i = 0; i < 8; ++i) {
        const int r = rr + i * 16;
        const float4 f = *(const float4*)(kg + (size_t)r * DM_ + cc);
        const int so = ((((cc >> 3) ^ (r & 7)) << 3) | (cc & 4));
        *(uint2*)(kd + r * 64 + so) = make_uint2(pack_bf16(f.x, f.y), pack_bf16(f.z, f.w));
      }
    }
    {
      const float* vg = v + ((size_t)(b * N_ + nb * BLK_)) * DM_ + h * DK_;
#pragma unroll
      for (int i = 0; i < 8; ++i) {
        const int r = rr + i * 16;
        const float4 f = *(const float4*)(vg + (size_t)r * DM_ + cc);
        *(u32*)(&tile[r][cc])     = pack_bf16(f.x, f.y);
        *(u32*)(&tile[r][cc + 2]) = pack_bf16(f.z, f.w);
      }
      __syncthreads();
      // d = t&63: 64 distinct d per wave -> conflict-light column gather (R4 fix)
      const int d = t & 63, n0 = (t >> 6) * 32;
      u16* og = vimg + obase + d * 128;
#pragma unroll
      for (int j = 0; j < 32; j += 8) {
        u16 tmp[8];
#pragma unroll
        for (int x = 0; x < 8; ++x) tmp[x] = tile[n0 + j + x][d];
        uint4 w; __builtin_memcpy(&w, tmp, 16);
        const int chunk = (n0 + j) >> 3;
        *(uint4*)(og + ((chunk ^ (d & 7)) << 3)) = w;
      }
    }
  } else {
    // ---- mask + block_sparse -> flags {0,1,2} ----
    const int blk = blk0 - 512;
    const int kb = blk % TB_, qb = (blk / TB_) % TB_, b = blk / (TB_ * TB_);
    const int* mg = mask + (size_t)b * N_ * N_ + (size_t)(qb * BLK_) * N_ + kb * BLK_;
    int all1 = 1, any1 = 0;
    for (int i = t; i < BLK_ * BLK_ / 4; i += 256) {
      const int r = i >> 5, c = (i & 31) * 4;
      const int4 mv = *(const int4*)(mg + (size_t)r * N_ + c);
      all1 &= (mv.x != 0) & (mv.y != 0) & (mv.z != 0) & (mv.w != 0);
      any1 |= (mv.x != 0) | (mv.y != 0) | (mv.z != 0) | (mv.w != 0);
    }
    const int wv = t >> 6;
    const int wAll = __all(all1), wAny = __any(any1);
    if ((t & 63) == 0) { sAll[wv] = wAll; sAny[wv] = wAny; }
    __syncthreads();
    if (t == 0) {
      const int A = sAll[0] & sAll[1] & sAll[2] & sAll[3];
      const int O = sAny[0] | sAny[1] | sAny[2] | sAny[3];
      int f = 0;
      if (bs[qb * TB_ + kb] != 0 && O) f = A ? 1 : 2;
      flags[blk] = f;
    }
  }
}

// softmax phase for one q-sub-tile (stA = st0/st1, NT = 0/1). Macro (not a
// runtime-indexed array) so every register index stays compile-time constant.
#define SOFTMAX_PHASE(stA, NT) do {                                              \
    if (mix) {                                                                   \
      const int* mg = mask + (size_t)b * N_ * N_ + (size_t)qg[NT] * N_ + cur * BLK_; \
      _Pragma("unroll")                                                          \
      for (int kt = 0; kt < 8; ++kt) {                                           \
        const int4 mv = *(const int4*)(mg + kt * 16 + quad * 4);                 \
        if (!mv.x) stA[kt][0] = -1e30f;                                          \
        if (!mv.y) stA[kt][1] = -1e30f;                                          \
        if (!mv.z) stA[kt][2] = -1e30f;                                          \
        if (!mv.w) stA[kt][3] = -1e30f;                                          \
      }                                                                          \
    }                                                                            \
    float mx = -INFINITY;                                                        \
    _Pragma("unroll")                                                            \
    for (int kt = 0; kt < 8; ++kt)                                               \
      mx = fmaxf(mx, fmaxf(fmaxf(stA[kt][0], stA[kt][1]),                        \
                           fmaxf(stA[kt][2], stA[kt][3])));                      \
    mx = fmaxf(mx, __shfl_xor(mx, 16, 64));                                      \
    mx = fmaxf(mx, __shfl_xor(mx, 32, 64));                                      \
    m_true[NT] = fmaxf(m_true[NT], mx);                                          \
    const float mold = m_run[NT];                                                \
    float mnew = mold;                                                           \
    if (!__all(mx <= mold + 8.f)) {                                              \
      mnew = fmaxf(mold, mx);                                                    \
      const float alpha = __builtin_amdgcn_exp2f(mold - mnew);                   \
      l_run[NT] *= alpha;                                                        \
      _Pragma("unroll")                                                          \
      for (int mt = 0; mt < 4; ++mt)                                             \
        _Pragma("unroll")                                                        \
        for (int r = 0; r < 4; ++r) oacc[NT][mt][r] *= alpha;                    \
      m_run[NT] = mnew;                                                          \
    }                                                                            \
    const int qloc = wave * 32 + NT * 16 + col;                                  \
    float s = 0.f;                                                               \
    if (!mix) {                                                                  \
      _Pragma("unroll")                                                          \
      for (int kt = 0; kt < 8; ++kt) {                                           \
        const float p0 = __builtin_amdgcn_exp2f(stA[kt][0] - mnew);              \
        const float p1 = __builtin_amdgcn_exp2f(stA[kt][1] - mnew);              \
        const float p2 = __builtin_amdgcn_exp2f(stA[kt][2] - mnew);              \
        const float p3 = __builtin_amdgcn_exp2f(stA[kt][3] - mnew);              \
        s += (p0 + p1) + (p2 + p3);                                              \
        *(uint2*)(Ps + qloc * PPAD + kt * 16 + quad * 4) =                       \
            make_uint2(pack_bf16(p0, p1), pack_bf16(p2, p3));                    \
      }                                                                          \
    } else {                                                                     \
      _Pragma("unroll")                                                          \
      for (int kt = 0; kt < 8; ++kt) {                                           \
        const float p0 = stA[kt][0] <= -1e29f ? 0.f : __builtin_amdgcn_exp2f(stA[kt][0] - mnew); \
        const float p1 = stA[kt][1] <= -1e29f ? 0.f : __builtin_amdgcn_exp2f(stA[kt][1] - mnew); \
        const float p2 = stA[kt][2] <= -1e29f ? 0.f : __builtin_amdgcn_exp2f(stA[kt][2] - mnew); \
        const float p3 = stA[kt][3] <= -1e29f ? 0.f : __builtin_amdgcn_exp2f(stA[kt][3] - mnew); \
        s += (p0 + p1) + (p2 + p3);                                              \
        *(uint2*)(Ps + qloc * PPAD + kt * 16 + quad * 4) =                       \
            make_uint2(pack_bf16(p0, p1), pack_bf16(p2, p3));                    \
      }                                                                          \
    }                                                                            \
    s += __shfl_xor(s, 16, 64);                                                  \
    s += __shfl_xor(s, 32, 64);                                                  \
    l_run[NT] += s;                                                              \
  } while (0)

// ---------------- main: block-sparse flash attention ----------------
// R10 base (best measured: 48.2us) + joint-nt QK, the one R1 idea whose test was
// invalidated by an unrelated spill (prefetch arrays + lambda -- both long gone;
// VGPR was 88, joint QK adds ~32 live regs, well under the 256/wave cap at
// 2 waves/SIMD). Why joint QK: (1) K fragments read ONCE for both q-sub-tiles
// (32 -> 16 ds_read_b128/iter/wave); (2) in-order issue means the SM0/SM1 VALU
// chains (largest serial per-iter cost) now issue in the shadow of QK1's MFMAs
// instead of strictly after their own QK -- MfmaUtil 12% + VALUBusy 26% say the
// two pipes currently ping-pong serially. Spill tripwire: WRITE_SIZE must stay
// ~17MB (R1's failure signature was +94MB).
__global__ __launch_bounds__(256, 2)
void attn_kernel(const float* __restrict__ q_, const u16* __restrict__ kimg,
                 const u16* __restrict__ vimg, const float* __restrict__ tau_p,
                 const int* __restrict__ mask, const int* __restrict__ flags,
                 float* __restrict__ o_out, float* __restrict__ l_out,
                 float* __restrict__ m_out) {
  __shared__ __align__(16) u16 lds[8192 + 8192 + BLK_ * PPAD];   // 67584 B
  u16* Ps  = lds + 16384;                 // 128 x PPAD (wave-private 32-row stripes)
  float* Os = (float*)lds;                // 128 x OPAD fp32 epilogue overlay (34816 B)

  const int idx = blockIdx.x;
  const int bh = idx & 31, qb128 = idx >> 5;
  const int b = bh >> 4, h = bh & 15;
  const int t = threadIdx.x;
  const int wave = t >> 6, lane = t & 63, quad = lane >> 4, col = lane & 15;

  // active-kb bitmasks (uniform across the WG)
  const int* flg = flags + (b * TB_ + qb128) * TB_;
  u32 actmask = 0, mixmask = 0;
#pragma unroll
  for (int i = 0; i < TB_; ++i) {
    const int f = flg[i];
    actmask |= (f != 0) ? (1u << i) : 0u;
    mixmask |= (f == 2) ? (1u << i) : 0u;
  }

  const u16* kpl = kimg + (size_t)(b * H_ + h) * TB_ * 8192;
  const u16* vpl = vimg + (size_t)(b * H_ + h) * TB_ * 8192;

  int qg[2];
  qg[0] = qb128 * BLK_ + wave * 32 + col;
  qg[1] = qg[0] + 16;

  // Q B-fragments from fp32 global (one-time; scale + log2e folded)
  const float qscale = tau_p[0] * 0.125f * 1.44269504f;
  bf16x8 bq[2][2];
#pragma unroll
  for (int nt = 0; nt < 2; ++nt) {
    const float* qr = q_ + ((size_t)(b * N_ + qg[nt])) * DM_ + h * DK_;
#pragma unroll
    for (int half = 0; half < 2; ++half) {
      const float4 f0 = *(const float4*)(qr + half * 32 + quad * 8);
      const float4 f1 = *(const float4*)(qr + half * 32 + quad * 8 + 4);
      bq[nt][half] = pack8(f0, f1, qscale);
    }
  }

  float m_run[2]  = {-INFINITY, -INFINITY};   // softmax base (lags true max <= THR)
  float m_true[2] = {-INFINITY, -INFINITY};   // true running max (for l/m outputs)
  float l_run[2] = {0.f, 0.f};
  f32x4 oacc[2][4];
#pragma unroll
  for (int nt = 0; nt < 2; ++nt)
#pragma unroll
    for (int mt = 0; mt < 4; ++mt) oacc[nt][mt] = (f32x4){0.f, 0.f, 0.f, 0.f};

  const int s8 = col & 7;                 // (fragment row) & 7 for K and V reads
  const int a0o = (quad ^ s8) << 3;       // swizzled 16B-chunk offset (u16 units)

  u32 rem = actmask;
  while (rem) {
    const int cur = (int)__builtin_ctz(rem);
    rem &= rem - 1;
    const int mix = (mixmask >> cur) & 1;

    __syncthreads();  // previous iter's K/V fragment reads complete
    // ---- register staging from contiguous image blocks (R4/R10-style; compiler
    //      interleaves ds_writes under progressive vmcnt) ----
    {
      const u16* ks = kpl + (size_t)cur * 8192;
      const u16* vs = vpl + (size_t)cur * 8192;
      uint4 kr[4], vr[4];
#pragma unroll
      for (int j = 0; j < 4; ++j) {
        const int i = (t + 256 * j) * 8;
        kr[j] = *(const uint4*)(ks + i);
        vr[j] = *(const uint4*)(vs + i);
      }
#pragma unroll
      for (int j = 0; j < 4; ++j) {
        const int i = (t + 256 * j) * 8;
        *(uint4*)(lds + i) = kr[j];
        *(uint4*)(lds + 8192 + i) = vr[j];
      }
    }
    __syncthreads();

    // ---- joint QK: K fragments read once, two independent accumulator chains ----
    f32x4 st0[8], st1[8];
    __builtin_amdgcn_s_setprio(1);
#pragma unroll
    for (int kt = 0; kt < 8; ++kt) {
      const u16* krow = lds + (kt * 16 + col) * 64;
      const bf16x8 a0 = *(const bf16x8*)(krow + a0o);
      const bf16x8 a1 = *(const bf16x8*)(krow + (a0o ^ 32));
      f32x4 c0 = (f32x4){0.f, 0.f, 0.f, 0.f};
      f32x4 c1 = (f32x4){0.f, 0.f, 0.f, 0.f};
      c0 = __builtin_amdgcn_mfma_f32_16x16x32_bf16(a0, bq[0][0], c0, 0, 0, 0);
      c1 = __builtin_amdgcn_mfma_f32_16x16x32_bf16(a0, bq[1][0], c1, 0, 0, 0);
      c0 = __builtin_amdgcn_mfma_f32_16x16x32_bf16(a1, bq[0][1], c0, 0, 0, 0);
      c1 = __builtin_amdgcn_mfma_f32_16x16x32_bf16(a1, bq[1][1], c1, 0, 0, 0);
      st0[kt] = c0;
      st1[kt] = c1;
    }
    __builtin_amdgcn_s_setprio(0);

    // ---- softmax chains issue in the MFMA shadow of the joint-QK cluster ----
    SOFTMAX_PHASE(st0, 0);
    SOFTMAX_PHASE(st1, 1);

    // ---- O^T += V^T . P^T ; P from wave-private LDS, swizzled V reads ----
    __builtin_amdgcn_s_setprio(1);
#pragma unroll
    for (int ks = 0; ks < 4; ++ks) {
      bf16x8 bfrag[2];
#pragma unroll
      for (int nt = 0; nt < 2; ++nt)
        bfrag[nt] = *(const bf16x8*)(Ps + (wave * 32 + nt * 16 + col) * PPAD + ks * 32 + quad * 8);
#pragma unroll
      for (int mt = 0; mt < 4; ++mt) {
        const bf16x8 av =
            *(const bf16x8*)(lds + 8192 + (mt * 16 + col) * 128 + (((ks * 4 + quad) ^ s8) << 3));
        oacc[0][mt] = __builtin_amdgcn_mfma_f32_16x16x32_bf16(av, bfrag[0], oacc[0][mt], 0, 0, 0);
        oacc[1][mt] = __builtin_amdgcn_mfma_f32_16x16x32_bf16(av, bfrag[1], oacc[1][mt], 0, 0, 0);
      }
    }
    __builtin_amdgcn_s_setprio(0);
  }

  // ---- epilogue: normalize, transpose O through LDS overlay, coalesced writes ----
  __syncthreads();  // all waves done with K/V/Ps before Os overlay
#pragma unroll
  for (int nt = 0; nt < 2; ++nt) {
    const float inv = l_run[nt] > 0.f ? 1.f / l_run[nt] : 1.f;
    const int qloc = wave * 32 + nt * 16 + col;
#pragma unroll
    for (int mt = 0; mt < 4; ++mt) {
      float4 w = make_float4(oacc[nt][mt][0] * inv, oacc[nt][mt][1] * inv,
                             oacc[nt][mt][2] * inv, oacc[nt][mt][3] * inv);
      *(float4*)(Os + qloc * OPAD + mt * 16 + quad * 4) = w;
    }
  }
  __syncthreads();
  float* ob = o_out + ((size_t)(b * N_ + qb128 * BLK_)) * DM_ + h * DK_;
#pragma unroll
  for (int j = 0; j < 8; ++j) {
    const int i = t + 256 * j;
    const int r = i >> 4, c4 = (i & 15) * 4;
    const float4 w = *(const float4*)(Os + r * OPAD + c4);
    *(float4*)(ob + (size_t)r * DM_ + c4) = w;
  }
  if (quad == 0) {
#pragma unroll
    for (int nt = 0; nt < 2; ++nt) {
      const size_t oi = (size_t)(b * H_ + h) * N_ + qg[nt];
      const float lv = l_run[nt] > 0.f
          ? l_run[nt] * __builtin_amdgcn_exp2f(m_run[nt] - m_true[nt]) : 0.f;
      l_out[oi] = lv;
      m_out[oi] = l_run[nt] > 0.f ? m_true[nt] * 0.69314718056f : -INFINITY;
    }
  }
}

extern "C" void kernel_launch(void* const* d_in, const int* in_sizes, int n_in,
                              void* d_out, int out_size, void* d_ws, size_t ws_size,
                              hipStream_t stream) {
  const float* q   = (const float*)d_in[0];
  const float* k   = (const float*)d_in[1];
  const float* v   = (const float*)d_in[2];
  const float* tau = (const float*)d_in[3];
  const int* mask  = (const int*)d_in[4];
  const int* bs    = (const int*)d_in[5];
  float* out = (float*)d_out;

  const size_t plane = (size_t)B_ * H_ * N_ * DK_;  // == B*H*TB*8192
  u16* kimg = (u16*)d_ws;
  u16* vimg = kimg + plane;
  int* flags = (int*)(vimg + plane);

  prepass_kernel<<<dim3(1024), 256, 0, stream>>>(k, v, mask, bs, kimg, vimg, flags);

  float* o_out = out;
  float* l_out = out + (size_t)B_ * N_ * DM_;
  float* m_out = l_out + (size_t)B_ * H_ * N_;
  attn_kernel<<<dim3(TB_ * 32), 256, 0, stream>>>(q, kimg, vimg, tau, mask, flags,
                                                  o_out, l_out, m_out);
}